// Round 1
// baseline (1161.885 us; speedup 1.0000x reference)
//
#include <hip/hip_runtime.h>
#include <math.h>

constexpr int NN = 100000;
constexpr int NE = 1600000;
constexpr int NG = 512;

__device__ __forceinline__ float eluf(float x) {
    return x > 0.f ? x : expm1f(x);
}

// float atomic max via signed-max / unsigned-min idiom (works with -inf init)
__device__ __forceinline__ void atomic_max_float(float* addr, float val) {
    if (val >= 0.f)
        atomicMax((int*)addr, __float_as_int(val));
    else
        atomicMin((unsigned int*)addr, __float_as_uint(val));
}

// zero counts/stats/meanacc, set maxacc = -inf
__global__ void k_init_small(float* __restrict__ counts, float* __restrict__ meanacc,
                             float* __restrict__ maxacc, float* __restrict__ stats) {
    int t = blockIdx.x * blockDim.x + threadIdx.x;
    if (t < NG) counts[t] = 0.f;
    if (t < NG * 32) { meanacc[t] = 0.f; maxacc[t] = -INFINITY; }
    if (t < 384) stats[t] = 0.f;
}

__global__ void k_deg(const int* __restrict__ dst, float* __restrict__ deg) {
    int e = blockIdx.x * blockDim.x + threadIdx.x;
    if (e < NE) unsafeAtomicAdd(&deg[dst[e]], 1.0f);
}

__global__ void k_dinv(float* __restrict__ deg_dinv) {
    int n = blockIdx.x * blockDim.x + threadIdx.x;
    if (n < NN) deg_dinv[n] = rsqrtf(deg_dinv[n] + 1.0f);
}

// out[n][c] = dot(X[n][:K], W[:,c]); 64/32 consecutive threads share one row n
template<int K, int C>
__global__ void k_gemm_rows(const float* __restrict__ X, const float* __restrict__ W,
                            float* __restrict__ out) {
    int t = blockIdx.x * blockDim.x + threadIdx.x;
    if (t >= NN * C) return;
    int c = t & (C - 1);
    int n = t / C;
    const float* xr = X + n * K;
    float acc = 0.f;
#pragma unroll
    for (int k = 0; k < K; ++k) acc = fmaf(xr[k], W[k * C + c], acc);
    out[t] = acc;
}

// one wave-fragment (C lanes) per edge: coalesced gather + coalesced atomic scatter
template<int C>
__global__ void k_scatter(const int* __restrict__ src, const int* __restrict__ dst,
                          const float* __restrict__ dinv, const float* __restrict__ xw,
                          float* __restrict__ agg) {
    int t = blockIdx.x * blockDim.x + threadIdx.x;
    int e = t / C;
    int c = t & (C - 1);
    if (e >= NE) return;
    int s = src[e], d = dst[e];
    float coef = dinv[s] * dinv[d];
    unsafeAtomicAdd(&agg[d * C + c], xw[s * C + c] * coef);
}

// agg += xw * dinv^2 (self loop), accumulate per-column sum / sumsq
template<int C>
__global__ void k_self_stats(const float* __restrict__ xw, const float* __restrict__ dinv,
                             float* __restrict__ agg, float* __restrict__ sums,
                             float* __restrict__ sqs) {
    constexpr int RPB = 256 / C;
    int c = threadIdx.x & (C - 1);
    int r = threadIdx.x / C;
    float s = 0.f, sq = 0.f;
    for (int n = blockIdx.x * RPB + r; n < NN; n += gridDim.x * RPB) {
        float di = dinv[n];
        int idx = n * C + c;
        float v = agg[idx] + xw[idx] * di * di;
        agg[idx] = v;
        s += v; sq += v * v;
    }
    __shared__ float red[256];
    red[threadIdx.x] = s;
    __syncthreads();
    if (threadIdx.x < C) {
        float tot = 0.f;
#pragma unroll
        for (int i = 0; i < RPB; ++i) tot += red[threadIdx.x + i * C];
        unsafeAtomicAdd(&sums[threadIdx.x], tot);
    }
    __syncthreads();
    red[threadIdx.x] = sq;
    __syncthreads();
    if (threadIdx.x < C) {
        float tot = 0.f;
#pragma unroll
        for (int i = 0; i < RPB; ++i) tot += red[threadIdx.x + i * C];
        unsafeAtomicAdd(&sqs[threadIdx.x], tot);
    }
}

template<int C>
__global__ void k_stats_fin(const float* __restrict__ sums, const float* __restrict__ sqs,
                            const float* __restrict__ gamma, const float* __restrict__ beta,
                            float* __restrict__ scale, float* __restrict__ shift) {
    int c = threadIdx.x;
    if (c < C) {
        float mu = sums[c] * (1.0f / NN);
        float var = sqs[c] * (1.0f / NN) - mu * mu;
        float sc = gamma[c] * rsqrtf(var + 1e-5f);
        scale[c] = sc;
        shift[c] = beta[c] - mu * sc;
    }
}

template<int C>
__global__ void k_bn_elu(const float* __restrict__ agg, const float* __restrict__ scale,
                         const float* __restrict__ shift, float* __restrict__ out) {
    int t = blockIdx.x * blockDim.x + threadIdx.x;
    if (t >= NN * C) return;
    int c = t & (C - 1);
    out[t] = eluf(fmaf(agg[t], scale[c], shift[c]));
}

__global__ void k_pool(const float* __restrict__ h2, const int* __restrict__ batch,
                       float* __restrict__ meanacc, float* __restrict__ maxacc,
                       float* __restrict__ counts) {
    int t = blockIdx.x * blockDim.x + threadIdx.x;
    int n = t >> 5, c = t & 31;
    if (n >= NN) return;
    int g = batch[n];
    float v = h2[t];
    unsafeAtomicAdd(&meanacc[g * 32 + c], v);
    atomic_max_float(&maxacc[g * 32 + c], v);
    if (c == 0) unsafeAtomicAdd(&counts[g], 1.0f);
}

__global__ void k_mlp(const float* __restrict__ meanacc, const float* __restrict__ maxacc,
                      const float* __restrict__ counts,
                      const float* __restrict__ Wm1, const float* __restrict__ bm1,
                      const float* __restrict__ Wm2, const float* __restrict__ bm2,
                      float* __restrict__ out) {
    int g = blockIdx.x;
    int t = threadIdx.x; // 64
    __shared__ float gr[64];
    __shared__ float h[32];
    float cnt = counts[g];
    if (t < 32) {
        gr[t] = meanacc[g * 32 + t] / fmaxf(cnt, 1.0f);
    } else {
        int c = t - 32;
        gr[t] = (cnt > 0.f) ? maxacc[g * 32 + c] : 0.f;
    }
    __syncthreads();
    if (t < 32) {
        float acc = bm1[t];
#pragma unroll
        for (int k = 0; k < 64; ++k) acc = fmaf(gr[k], Wm1[k * 32 + t], acc);
        h[t] = eluf(acc);
    }
    __syncthreads();
    if (t < 2) {
        float acc = bm2[t];
#pragma unroll
        for (int k = 0; k < 32; ++k) acc = fmaf(h[k], Wm2[k * 2 + t], acc);
        out[g * 2 + t] = acc;
    }
}

extern "C" void kernel_launch(void* const* d_in, const int* in_sizes, int n_in,
                              void* d_out, int out_size, void* d_ws, size_t ws_size,
                              hipStream_t stream) {
    const float* x    = (const float*)d_in[0];
    const int*   eidx = (const int*)d_in[1];   // int32 (JAX x64 disabled)
    const int*   src  = eidx;
    const int*   dst  = eidx + NE;
    const int*   batch = (const int*)d_in[3];
    const float* W1  = (const float*)d_in[4];
    const float* g1  = (const float*)d_in[6];
    const float* be1 = (const float*)d_in[7];
    const float* W2  = (const float*)d_in[8];
    const float* g2  = (const float*)d_in[10];
    const float* be2 = (const float*)d_in[11];
    const float* Wm1 = (const float*)d_in[12];
    const float* bm1 = (const float*)d_in[13];
    const float* Wm2 = (const float*)d_in[14];
    const float* bm2 = (const float*)d_in[15];
    float* out = (float*)d_out;

    float* ws  = (float*)d_ws;
    float* dinv = ws;                      // NN floats (deg -> dinv in place)
    float* A = ws + 100032;                // 6.4M: xw1 -> h1 -> h2
    float* B = A + 6400000;                // 6.4M: agg1 -> [xw2 | agg2]
    float* S = B + 6400000;
    float* sum1 = S;          float* sq1 = S + 64;
    float* scale1 = S + 128;  float* shift1 = S + 192;
    float* sum2 = S + 256;    float* sq2 = S + 288;
    float* scale2 = S + 320;  float* shift2 = S + 352;
    float* counts  = S + 384;              // 512
    float* meanacc = S + 896;              // 512*32
    float* maxacc  = meanacc + NG * 32;    // 512*32
    float* xw1  = A;
    float* agg1 = B;
    float* h1   = A;
    float* xw2  = B;
    float* agg2 = B + 3200000;
    float* h2   = A;

    // zero accumulators (ws is poisoned before every timed call)
    hipMemsetAsync(dinv, 0, NN * sizeof(float), stream);
    hipMemsetAsync(agg1, 0, (size_t)6400000 * sizeof(float), stream);
    k_init_small<<<64, 256, 0, stream>>>(counts, meanacc, maxacc, sum1);

    // degree + dinv
    k_deg<<<NE / 256, 256, 0, stream>>>(dst, dinv);
    k_dinv<<<(NN + 255) / 256, 256, 0, stream>>>(dinv);

    // layer 1: xw1 = x @ W1  (bias dropped: BN is shift-invariant)
    k_gemm_rows<66, 64><<<NN * 64 / 256, 256, 0, stream>>>(x, W1, xw1);
    k_scatter<64><<<NE * 64 / 256, 256, 0, stream>>>(src, dst, dinv, xw1, agg1);
    k_self_stats<64><<<512, 256, 0, stream>>>(xw1, dinv, agg1, sum1, sq1);
    k_stats_fin<64><<<1, 64, 0, stream>>>(sum1, sq1, g1, be1, scale1, shift1);
    k_bn_elu<64><<<NN * 64 / 256, 256, 0, stream>>>(agg1, scale1, shift1, h1);

    // layer 2
    k_gemm_rows<64, 32><<<NN * 32 / 256, 256, 0, stream>>>(h1, W2, xw2);
    hipMemsetAsync(agg2, 0, (size_t)3200000 * sizeof(float), stream);
    k_scatter<32><<<NE * 32 / 256, 256, 0, stream>>>(src, dst, dinv, xw2, agg2);
    k_self_stats<32><<<512, 256, 0, stream>>>(xw2, dinv, agg2, sum2, sq2);
    k_stats_fin<32><<<1, 32, 0, stream>>>(sum2, sq2, g2, be2, scale2, shift2);
    k_bn_elu<32><<<NN * 32 / 256, 256, 0, stream>>>(agg2, scale2, shift2, h2);

    // pooling + MLP head
    k_pool<<<NN * 32 / 256, 256, 0, stream>>>(h2, batch, meanacc, maxacc, counts);
    k_mlp<<<NG, 64, 0, stream>>>(meanacc, maxacc, counts, Wm1, bm1, Wm2, bm2, out);
}

// Round 2
// 1076.187 us; speedup vs baseline: 1.0796x; 1.0796x over previous
//
#include <hip/hip_runtime.h>
#include <math.h>

constexpr int NN = 100000;
constexpr int NE = 1600000;
constexpr int NG = 512;
constexpr int NBLK = (NN + 255) / 256;   // 391 scan blocks

__device__ __forceinline__ float eluf(float x) {
    return x > 0.f ? x : expm1f(x);
}

// float atomic max via signed-max / unsigned-min idiom (works with -inf init)
__device__ __forceinline__ void atomic_max_float(float* addr, float val) {
    if (val >= 0.f)
        atomicMax((int*)addr, __float_as_int(val));
    else
        atomicMin((unsigned int*)addr, __float_as_uint(val));
}

// zero counts/stats/meanacc, set maxacc = -inf  (grid 64x256 = 16384 threads)
__global__ void k_init_small(float* __restrict__ counts, float* __restrict__ meanacc,
                             float* __restrict__ maxacc, float* __restrict__ stats) {
    int t = blockIdx.x * blockDim.x + threadIdx.x;
    if (t < NG) counts[t] = 0.f;
    if (t < NG * 32) { meanacc[t] = 0.f; maxacc[t] = -INFINITY; }
    if (t < 384) stats[t] = 0.f;
}

__global__ void k_deg(const int* __restrict__ dst, int* __restrict__ deg) {
    int e = blockIdx.x * blockDim.x + threadIdx.x;
    if (e < NE) atomicAdd(&deg[dst[e]], 1);
}

__global__ void k_dinv(const int* __restrict__ deg, float* __restrict__ dinv) {
    int n = blockIdx.x * blockDim.x + threadIdx.x;
    if (n < NN) dinv[n] = rsqrtf((float)deg[n] + 1.0f);
}

// --- 3-kernel exclusive scan of deg -> rowptr (and cursor copy) ---
__global__ void k_scan_block(const int* __restrict__ deg, int* __restrict__ tmp,
                             int* __restrict__ part) {
    __shared__ int sh[256];
    int tid = threadIdx.x;
    int i = blockIdx.x * 256 + tid;
    int v = (i < NN) ? deg[i] : 0;
    sh[tid] = v;
    __syncthreads();
    for (int off = 1; off < 256; off <<= 1) {
        int t = (tid >= off) ? sh[tid - off] : 0;
        __syncthreads();
        sh[tid] += t;
        __syncthreads();
    }
    if (i < NN) tmp[i] = sh[tid] - v;          // exclusive within block
    if (tid == 255) part[blockIdx.x] = sh[255];
}

__global__ void k_scan_part(int* __restrict__ part) {   // one block of 512
    __shared__ int sh[512];
    int tid = threadIdx.x;
    int v = (tid < NBLK) ? part[tid] : 0;
    sh[tid] = v;
    __syncthreads();
    for (int off = 1; off < 512; off <<= 1) {
        int t = (tid >= off) ? sh[tid - off] : 0;
        __syncthreads();
        sh[tid] += t;
        __syncthreads();
    }
    if (tid < NBLK) part[tid] = sh[tid] - v;   // exclusive block offsets
}

__global__ void k_scan_fin(const int* __restrict__ tmp, const int* __restrict__ part,
                           int* __restrict__ rowptr, int* __restrict__ cursor) {
    int i = blockIdx.x * 256 + threadIdx.x;
    if (i < NN) {
        int r = tmp[i] + part[i >> 8];
        rowptr[i] = r;
        cursor[i] = r;
    }
    if (i == 0) rowptr[NN] = NE;
}

// place edges into CSR buckets; precompute coef = dinv[s]*dinv[d]
__global__ void k_place(const int* __restrict__ src, const int* __restrict__ dst,
                        const float* __restrict__ dinv, int* __restrict__ cursor,
                        int* __restrict__ csr_src, float* __restrict__ csr_coef) {
    int e = blockIdx.x * blockDim.x + threadIdx.x;
    if (e >= NE) return;
    int s = src[e], d = dst[e];
    int pos = atomicAdd(&cursor[d], 1);
    csr_src[pos] = s;
    csr_coef[pos] = dinv[s] * dinv[d];
}

// out[n][c] = dot(X[n][:K], W[:,c]); C consecutive threads share one row n
template<int K, int C>
__global__ void k_gemm_rows(const float* __restrict__ X, const float* __restrict__ W,
                            float* __restrict__ out) {
    int t = blockIdx.x * blockDim.x + threadIdx.x;
    if (t >= NN * C) return;
    int c = t & (C - 1);
    int n = t / C;
    const float* xr = X + n * K;
    float acc = 0.f;
#pragma unroll
    for (int k = 0; k < K; ++k) acc = fmaf(xr[k], W[k * C + c], acc);
    out[t] = acc;
}

// CSR gather: C lanes per node (lanes = columns); one coalesced 4*C-byte read
// per in-edge, one plain write per output. Self-loop + BN-stats fused.
template<int C>
__global__ void k_gather(const int* __restrict__ rowptr, const int* __restrict__ csr_src,
                         const float* __restrict__ csr_coef, const float* __restrict__ dinv,
                         const float* __restrict__ xw, float* __restrict__ agg,
                         float* __restrict__ sums, float* __restrict__ sqs) {
    constexpr int NPB = 256 / C;
    int c = threadIdx.x & (C - 1);
    int local = threadIdx.x / C;
    float s_acc = 0.f, sq_acc = 0.f;
    for (int n = blockIdx.x * NPB + local; n < NN; n += gridDim.x * NPB) {
        int beg = rowptr[n], end = rowptr[n + 1];
        float acc = 0.f;
        for (int j = beg; j < end; ++j)
            acc = fmaf(xw[csr_src[j] * C + c], csr_coef[j], acc);
        float di = dinv[n];
        acc = fmaf(xw[n * C + c], di * di, acc);   // self loop
        agg[n * C + c] = acc;
        s_acc += acc;
        sq_acc += acc * acc;
    }
    __shared__ float red[256];
    red[threadIdx.x] = s_acc;
    __syncthreads();
    if (threadIdx.x < C) {
        float tot = 0.f;
#pragma unroll
        for (int i = 0; i < NPB; ++i) tot += red[threadIdx.x + i * C];
        unsafeAtomicAdd(&sums[threadIdx.x], tot);
    }
    __syncthreads();
    red[threadIdx.x] = sq_acc;
    __syncthreads();
    if (threadIdx.x < C) {
        float tot = 0.f;
#pragma unroll
        for (int i = 0; i < NPB; ++i) tot += red[threadIdx.x + i * C];
        unsafeAtomicAdd(&sqs[threadIdx.x], tot);
    }
}

template<int C>
__global__ void k_stats_fin(const float* __restrict__ sums, const float* __restrict__ sqs,
                            const float* __restrict__ gamma, const float* __restrict__ beta,
                            float* __restrict__ scale, float* __restrict__ shift) {
    int c = threadIdx.x;
    if (c < C) {
        float mu = sums[c] * (1.0f / NN);
        float var = sqs[c] * (1.0f / NN) - mu * mu;
        float sc = gamma[c] * rsqrtf(var + 1e-5f);
        scale[c] = sc;
        shift[c] = beta[c] - mu * sc;
    }
}

template<int C>
__global__ void k_bn_elu(const float* __restrict__ agg, const float* __restrict__ scale,
                         const float* __restrict__ shift, float* __restrict__ out) {
    int t = blockIdx.x * blockDim.x + threadIdx.x;
    if (t >= NN * C) return;
    int c = t & (C - 1);
    out[t] = eluf(fmaf(agg[t], scale[c], shift[c]));
}

// layer-2 BN+ELU fused directly into pooling (h2 never materialized)
__global__ void k_bn_elu_pool(const float* __restrict__ agg, const float* __restrict__ scale,
                              const float* __restrict__ shift, const int* __restrict__ batch,
                              float* __restrict__ meanacc, float* __restrict__ maxacc,
                              float* __restrict__ counts) {
    int t = blockIdx.x * blockDim.x + threadIdx.x;
    if (t >= NN * 32) return;
    int n = t >> 5, c = t & 31;
    float v = eluf(fmaf(agg[t], scale[c], shift[c]));
    int g = batch[n];
    unsafeAtomicAdd(&meanacc[g * 32 + c], v);
    atomic_max_float(&maxacc[g * 32 + c], v);
    if (c == 0) unsafeAtomicAdd(&counts[g], 1.0f);
}

__global__ void k_mlp(const float* __restrict__ meanacc, const float* __restrict__ maxacc,
                      const float* __restrict__ counts,
                      const float* __restrict__ Wm1, const float* __restrict__ bm1,
                      const float* __restrict__ Wm2, const float* __restrict__ bm2,
                      float* __restrict__ out) {
    int g = blockIdx.x;
    int t = threadIdx.x; // 64
    __shared__ float gr[64];
    __shared__ float h[32];
    float cnt = counts[g];
    if (t < 32) {
        gr[t] = meanacc[g * 32 + t] / fmaxf(cnt, 1.0f);
    } else {
        int c = t - 32;
        gr[t] = (cnt > 0.f) ? maxacc[g * 32 + c] : 0.f;
    }
    __syncthreads();
    if (t < 32) {
        float acc = bm1[t];
#pragma unroll
        for (int k = 0; k < 64; ++k) acc = fmaf(gr[k], Wm1[k * 32 + t], acc);
        h[t] = eluf(acc);
    }
    __syncthreads();
    if (t < 2) {
        float acc = bm2[t];
#pragma unroll
        for (int k = 0; k < 32; ++k) acc = fmaf(h[k], Wm2[k * 2 + t], acc);
        out[g * 2 + t] = acc;
    }
}

extern "C" void kernel_launch(void* const* d_in, const int* in_sizes, int n_in,
                              void* d_out, int out_size, void* d_ws, size_t ws_size,
                              hipStream_t stream) {
    const float* x    = (const float*)d_in[0];
    const int*   eidx = (const int*)d_in[1];
    const int*   src  = eidx;
    const int*   dst  = eidx + NE;
    const int*   batch = (const int*)d_in[3];
    const float* W1  = (const float*)d_in[4];
    const float* g1  = (const float*)d_in[6];
    const float* be1 = (const float*)d_in[7];
    const float* W2  = (const float*)d_in[8];
    const float* g2  = (const float*)d_in[10];
    const float* be2 = (const float*)d_in[11];
    const float* Wm1 = (const float*)d_in[12];
    const float* bm1 = (const float*)d_in[13];
    const float* Wm2 = (const float*)d_in[14];
    const float* bm2 = (const float*)d_in[15];
    float* out = (float*)d_out;

    // ---- workspace layout ----
    int*   deg_i    = (int*)d_ws;                  // 100000
    int*   rowptr   = deg_i + 100000;              // 100001 (+pad)
    int*   cursor   = rowptr + 100032;             // 100000
    int*   tmp      = cursor + 100000;             // 100000
    int*   part     = tmp + 100000;                // 512
    int*   csr_src  = part + 512;                  // 1600000
    float* csr_coef = (float*)(csr_src + 1600000); // 1600000
    float* dinv     = csr_coef + 1600000;          // 100000
    float* S        = dinv + 100000;               // 33664 (stats + pools)
    float* A        = S + 33664;                   // 6400000: xw1 -> h1
    float* B        = A + 6400000;                 // 6400000: agg1 -> [xw2|agg2]

    float* sum1 = S;          float* sq1 = S + 64;
    float* scale1 = S + 128;  float* shift1 = S + 192;
    float* sum2 = S + 256;    float* sq2 = S + 288;
    float* scale2 = S + 320;  float* shift2 = S + 352;
    float* counts  = S + 384;              // 512
    float* meanacc = S + 896;              // 512*32
    float* maxacc  = meanacc + NG * 32;    // 512*32

    float* xw1  = A;
    float* agg1 = B;
    float* h1   = A;
    float* xw2  = B;
    float* agg2 = B + 3200000;

    // ---- init ----
    hipMemsetAsync(deg_i, 0, NN * sizeof(int), stream);
    k_init_small<<<64, 256, 0, stream>>>(counts, meanacc, maxacc, sum1);

    // ---- degree / dinv / CSR build ----
    k_deg<<<NE / 256, 256, 0, stream>>>(dst, deg_i);
    k_dinv<<<NBLK, 256, 0, stream>>>(deg_i, dinv);
    k_scan_block<<<NBLK, 256, 0, stream>>>(deg_i, tmp, part);
    k_scan_part<<<1, 512, 0, stream>>>(part);
    k_scan_fin<<<NBLK, 256, 0, stream>>>(tmp, part, rowptr, cursor);
    k_place<<<NE / 256, 256, 0, stream>>>(src, dst, dinv, cursor, csr_src, csr_coef);

    // ---- layer 1 (bias dropped: BN is shift-invariant) ----
    k_gemm_rows<66, 64><<<NN * 64 / 256, 256, 0, stream>>>(x, W1, xw1);
    k_gather<64><<<1024, 256, 0, stream>>>(rowptr, csr_src, csr_coef, dinv, xw1, agg1, sum1, sq1);
    k_stats_fin<64><<<1, 64, 0, stream>>>(sum1, sq1, g1, be1, scale1, shift1);
    k_bn_elu<64><<<NN * 64 / 256, 256, 0, stream>>>(agg1, scale1, shift1, h1);

    // ---- layer 2 ----
    k_gemm_rows<64, 32><<<NN * 32 / 256, 256, 0, stream>>>(h1, W2, xw2);
    k_gather<32><<<1024, 256, 0, stream>>>(rowptr, csr_src, csr_coef, dinv, xw2, agg2, sum2, sq2);
    k_stats_fin<32><<<1, 32, 0, stream>>>(sum2, sq2, g2, be2, scale2, shift2);

    // ---- BN+ELU fused with pooling, then MLP head ----
    k_bn_elu_pool<<<NN * 32 / 256, 256, 0, stream>>>(agg2, scale2, shift2, batch,
                                                     meanacc, maxacc, counts);
    k_mlp<<<NG, 64, 0, stream>>>(meanacc, maxacc, counts, Wm1, bm1, Wm2, bm2, out);
}

// Round 3
// 814.093 us; speedup vs baseline: 1.4272x; 1.3219x over previous
//
#include <hip/hip_runtime.h>
#include <math.h>

constexpr int NN = 100000;
constexpr int NE = 1600000;
constexpr int NG = 512;
constexpr int NBLK = (NN + 255) / 256;   // 391 scan blocks

__device__ __forceinline__ float eluf(float x) {
    return x > 0.f ? x : expm1f(x);
}

// float atomic max via signed-max / unsigned-min idiom (works with -inf init)
__device__ __forceinline__ void atomic_max_float(float* addr, float val) {
    if (val >= 0.f)
        atomicMax((int*)addr, __float_as_int(val));
    else
        atomicMin((unsigned int*)addr, __float_as_uint(val));
}

__global__ void k_init_small(float* __restrict__ counts, float* __restrict__ meanacc,
                             float* __restrict__ maxacc, float* __restrict__ stats) {
    int t = blockIdx.x * blockDim.x + threadIdx.x;
    if (t < NG) counts[t] = 0.f;
    if (t < NG * 32) { meanacc[t] = 0.f; maxacc[t] = -INFINITY; }
    if (t < 384) stats[t] = 0.f;
}

__global__ void k_deg(const int* __restrict__ dst, int* __restrict__ deg) {
    int e = blockIdx.x * blockDim.x + threadIdx.x;
    if (e < NE) atomicAdd(&deg[dst[e]], 1);
}

__global__ void k_dinv(const int* __restrict__ deg, float* __restrict__ dinv) {
    int n = blockIdx.x * blockDim.x + threadIdx.x;
    if (n < NN) dinv[n] = rsqrtf((float)deg[n] + 1.0f);
}

// --- 3-kernel exclusive scan of deg -> rowptr (and cursor copy) ---
__global__ void k_scan_block(const int* __restrict__ deg, int* __restrict__ tmp,
                             int* __restrict__ part) {
    __shared__ int sh[256];
    int tid = threadIdx.x;
    int i = blockIdx.x * 256 + tid;
    int v = (i < NN) ? deg[i] : 0;
    sh[tid] = v;
    __syncthreads();
    for (int off = 1; off < 256; off <<= 1) {
        int t = (tid >= off) ? sh[tid - off] : 0;
        __syncthreads();
        sh[tid] += t;
        __syncthreads();
    }
    if (i < NN) tmp[i] = sh[tid] - v;          // exclusive within block
    if (tid == 255) part[blockIdx.x] = sh[255];
}

__global__ void k_scan_part(int* __restrict__ part) {   // one block of 512
    __shared__ int sh[512];
    int tid = threadIdx.x;
    int v = (tid < NBLK) ? part[tid] : 0;
    sh[tid] = v;
    __syncthreads();
    for (int off = 1; off < 512; off <<= 1) {
        int t = (tid >= off) ? sh[tid - off] : 0;
        __syncthreads();
        sh[tid] += t;
        __syncthreads();
    }
    if (tid < NBLK) part[tid] = sh[tid] - v;   // exclusive block offsets
}

__global__ void k_scan_fin(const int* __restrict__ tmp, const int* __restrict__ part,
                           int* __restrict__ rowptr, int* __restrict__ cursor) {
    int i = blockIdx.x * 256 + threadIdx.x;
    if (i < NN) {
        int r = tmp[i] + part[i >> 8];
        rowptr[i] = r;
        cursor[i] = r;
    }
    if (i == 0) rowptr[NN] = NE;
}

// place edges into CSR buckets; ecsr = {src, coef} packed (one 8B store)
__global__ void k_place(const int* __restrict__ src, const int* __restrict__ dst,
                        const float* __restrict__ dinv, int* __restrict__ cursor,
                        int2* __restrict__ ecsr) {
    int e = blockIdx.x * blockDim.x + threadIdx.x;
    if (e >= NE) return;
    int s = src[e], d = dst[e];
    int pos = atomicAdd(&cursor[d], 1);
    ecsr[pos] = make_int2(s, __float_as_int(dinv[s] * dinv[d]));
}

// out[n][c] = dot(X[n][:K], W[:,c]); C consecutive threads share one row n
template<int K, int C>
__global__ void k_gemm_rows(const float* __restrict__ X, const float* __restrict__ W,
                            float* __restrict__ out) {
    int t = blockIdx.x * blockDim.x + threadIdx.x;
    if (t >= NN * C) return;
    int c = t & (C - 1);
    int n = t / C;
    const float* xr = X + n * K;
    float acc = 0.f;
#pragma unroll
    for (int k = 0; k < K; ++k) acc = fmaf(xr[k], W[k * C + c], acc);
    out[t] = acc;
}

// CSR gather, unrolled x8 for memory-level parallelism.
// C lanes per node (lanes = columns). Self-loop + BN-stats fused.
template<int C>
__global__ void k_gather(const int* __restrict__ rowptr, const int2* __restrict__ ecsr,
                         const float* __restrict__ dinv,
                         const float* __restrict__ xw, float* __restrict__ agg,
                         float* __restrict__ sums, float* __restrict__ sqs) {
    constexpr int NPB = 256 / C;
    int c = threadIdx.x & (C - 1);
    int local = threadIdx.x / C;
    float s_acc = 0.f, sq_acc = 0.f;
    for (int n = blockIdx.x * NPB + local; n < NN; n += gridDim.x * NPB) {
        int beg = rowptr[n], end = rowptr[n + 1];
        float acc = 0.f;
        int j = beg;
        for (; j + 8 <= end; j += 8) {
            int2 e0 = ecsr[j+0]; int2 e1 = ecsr[j+1];
            int2 e2 = ecsr[j+2]; int2 e3 = ecsr[j+3];
            int2 e4 = ecsr[j+4]; int2 e5 = ecsr[j+5];
            int2 e6 = ecsr[j+6]; int2 e7 = ecsr[j+7];
            float v0 = xw[e0.x * C + c]; float v1 = xw[e1.x * C + c];
            float v2 = xw[e2.x * C + c]; float v3 = xw[e3.x * C + c];
            float v4 = xw[e4.x * C + c]; float v5 = xw[e5.x * C + c];
            float v6 = xw[e6.x * C + c]; float v7 = xw[e7.x * C + c];
            acc = fmaf(v0, __int_as_float(e0.y), acc);
            acc = fmaf(v1, __int_as_float(e1.y), acc);
            acc = fmaf(v2, __int_as_float(e2.y), acc);
            acc = fmaf(v3, __int_as_float(e3.y), acc);
            acc = fmaf(v4, __int_as_float(e4.y), acc);
            acc = fmaf(v5, __int_as_float(e5.y), acc);
            acc = fmaf(v6, __int_as_float(e6.y), acc);
            acc = fmaf(v7, __int_as_float(e7.y), acc);
        }
        for (; j < end; ++j) {
            int2 e = ecsr[j];
            acc = fmaf(xw[e.x * C + c], __int_as_float(e.y), acc);
        }
        float di = dinv[n];
        acc = fmaf(xw[n * C + c], di * di, acc);   // self loop
        agg[n * C + c] = acc;
        s_acc += acc;
        sq_acc += acc * acc;
    }
    __shared__ float red[256];
    red[threadIdx.x] = s_acc;
    __syncthreads();
    if (threadIdx.x < C) {
        float tot = 0.f;
#pragma unroll
        for (int i = 0; i < NPB; ++i) tot += red[threadIdx.x + i * C];
        unsafeAtomicAdd(&sums[threadIdx.x], tot);
    }
    __syncthreads();
    red[threadIdx.x] = sq_acc;
    __syncthreads();
    if (threadIdx.x < C) {
        float tot = 0.f;
#pragma unroll
        for (int i = 0; i < NPB; ++i) tot += red[threadIdx.x + i * C];
        unsafeAtomicAdd(&sqs[threadIdx.x], tot);
    }
}

template<int C>
__global__ void k_stats_fin(const float* __restrict__ sums, const float* __restrict__ sqs,
                            const float* __restrict__ gamma, const float* __restrict__ beta,
                            float* __restrict__ scale, float* __restrict__ shift) {
    int c = threadIdx.x;
    if (c < C) {
        float mu = sums[c] * (1.0f / NN);
        float var = sqs[c] * (1.0f / NN) - mu * mu;
        float sc = gamma[c] * rsqrtf(var + 1e-5f);
        scale[c] = sc;
        shift[c] = beta[c] - mu * sc;
    }
}

// fused: h1 = elu(bn(agg1)) staged in LDS, then xw2 = h1 @ W2  (h1 never hits HBM)
__global__ void k_bn_gemm2(const float* __restrict__ agg1, const float* __restrict__ scale,
                           const float* __restrict__ shift, const float* __restrict__ W2,
                           float* __restrict__ xw2) {
    __shared__ float sh[8 * 64];
    __shared__ float sW[64 * 32];
    int tid = threadIdx.x;
#pragma unroll
    for (int i = tid; i < 64 * 32; i += 256) sW[i] = W2[i];
    int base = blockIdx.x * 8;
#pragma unroll
    for (int i = tid; i < 512; i += 256) {
        int r = i >> 6, cc = i & 63;
        int n = base + r;
        sh[i] = (n < NN) ? eluf(fmaf(agg1[n * 64 + cc], scale[cc], shift[cc])) : 0.f;
    }
    __syncthreads();
    int r = tid >> 5, c = tid & 31;   // 8 rows x 32 cols
    int n = base + r;
    if (n < NN) {
        float acc = 0.f;
#pragma unroll
        for (int k = 0; k < 64; ++k) acc = fmaf(sh[r * 64 + k], sW[k * 32 + c], acc);
        xw2[n * 32 + c] = acc;
    }
}

// layer-2 BN+ELU fused directly into pooling (h2 never materialized)
__global__ void k_bn_elu_pool(const float* __restrict__ agg, const float* __restrict__ scale,
                              const float* __restrict__ shift, const int* __restrict__ batch,
                              float* __restrict__ meanacc, float* __restrict__ maxacc,
                              float* __restrict__ counts) {
    int t = blockIdx.x * blockDim.x + threadIdx.x;
    if (t >= NN * 32) return;
    int n = t >> 5, c = t & 31;
    float v = eluf(fmaf(agg[t], scale[c], shift[c]));
    int g = batch[n];
    unsafeAtomicAdd(&meanacc[g * 32 + c], v);
    atomic_max_float(&maxacc[g * 32 + c], v);
    if (c == 0) unsafeAtomicAdd(&counts[g], 1.0f);
}

__global__ void k_mlp(const float* __restrict__ meanacc, const float* __restrict__ maxacc,
                      const float* __restrict__ counts,
                      const float* __restrict__ Wm1, const float* __restrict__ bm1,
                      const float* __restrict__ Wm2, const float* __restrict__ bm2,
                      float* __restrict__ out) {
    int g = blockIdx.x;
    int t = threadIdx.x; // 64
    __shared__ float gr[64];
    __shared__ float h[32];
    float cnt = counts[g];
    if (t < 32) {
        gr[t] = meanacc[g * 32 + t] / fmaxf(cnt, 1.0f);
    } else {
        int c = t - 32;
        gr[t] = (cnt > 0.f) ? maxacc[g * 32 + c] : 0.f;
    }
    __syncthreads();
    if (t < 32) {
        float acc = bm1[t];
#pragma unroll
        for (int k = 0; k < 64; ++k) acc = fmaf(gr[k], Wm1[k * 32 + t], acc);
        h[t] = eluf(acc);
    }
    __syncthreads();
    if (t < 2) {
        float acc = bm2[t];
#pragma unroll
        for (int k = 0; k < 32; ++k) acc = fmaf(h[k], Wm2[k * 2 + t], acc);
        out[g * 2 + t] = acc;
    }
}

extern "C" void kernel_launch(void* const* d_in, const int* in_sizes, int n_in,
                              void* d_out, int out_size, void* d_ws, size_t ws_size,
                              hipStream_t stream) {
    const float* x    = (const float*)d_in[0];
    const int*   eidx = (const int*)d_in[1];
    const int*   src  = eidx;
    const int*   dst  = eidx + NE;
    const int*   batch = (const int*)d_in[3];
    const float* W1  = (const float*)d_in[4];
    const float* g1  = (const float*)d_in[6];
    const float* be1 = (const float*)d_in[7];
    const float* W2  = (const float*)d_in[8];
    const float* g2  = (const float*)d_in[10];
    const float* be2 = (const float*)d_in[11];
    const float* Wm1 = (const float*)d_in[12];
    const float* bm1 = (const float*)d_in[13];
    const float* Wm2 = (const float*)d_in[14];
    const float* bm2 = (const float*)d_in[15];
    float* out = (float*)d_out;

    // ---- workspace layout ----
    int*   deg_i  = (int*)d_ws;                  // 100000
    int*   rowptr = deg_i + 100000;              // 100032 (incl +1 slot)
    int*   cursor = rowptr + 100032;             // 100000
    int*   tmp    = cursor + 100000;             // 100000
    int*   part   = tmp + 100000;                // 512
    int2*  ecsr   = (int2*)(part + 512);         // 1600000 int2 (8B aligned)
    float* dinv   = (float*)(ecsr + 1600000);    // 100000
    float* S      = dinv + 100000;               // 33664 (stats + pools)
    float* A      = S + 33664;                   // 6400000: xw1 -> [xw2|agg2]
    float* B      = A + 6400000;                 // 6400000: agg1

    float* sum1 = S;          float* sq1 = S + 64;
    float* scale1 = S + 128;  float* shift1 = S + 192;
    float* sum2 = S + 256;    float* sq2 = S + 288;
    float* scale2 = S + 320;  float* shift2 = S + 352;
    float* counts  = S + 384;              // 512
    float* meanacc = S + 896;              // 512*32
    float* maxacc  = meanacc + NG * 32;    // 512*32

    float* xw1  = A;
    float* agg1 = B;
    float* xw2  = A;                  // xw1 dead once agg1 + stats done
    float* agg2 = A + 3200000;

    // ---- init ----
    hipMemsetAsync(deg_i, 0, NN * sizeof(int), stream);
    k_init_small<<<64, 256, 0, stream>>>(counts, meanacc, maxacc, sum1);

    // ---- degree / dinv / CSR build ----
    k_deg<<<NE / 256, 256, 0, stream>>>(dst, deg_i);
    k_dinv<<<NBLK, 256, 0, stream>>>(deg_i, dinv);
    k_scan_block<<<NBLK, 256, 0, stream>>>(deg_i, tmp, part);
    k_scan_part<<<1, 512, 0, stream>>>(part);
    k_scan_fin<<<NBLK, 256, 0, stream>>>(tmp, part, rowptr, cursor);
    k_place<<<NE / 256, 256, 0, stream>>>(src, dst, dinv, cursor, ecsr);

    // ---- layer 1 (bias dropped: BN is shift-invariant) ----
    k_gemm_rows<66, 64><<<NN * 64 / 256, 256, 0, stream>>>(x, W1, xw1);
    k_gather<64><<<2048, 256, 0, stream>>>(rowptr, ecsr, dinv, xw1, agg1, sum1, sq1);
    k_stats_fin<64><<<1, 64, 0, stream>>>(sum1, sq1, g1, be1, scale1, shift1);

    // ---- layer 2 (BN+ELU of layer 1 fused into the GEMM) ----
    k_bn_gemm2<<<(NN + 7) / 8, 256, 0, stream>>>(agg1, scale1, shift1, W2, xw2);
    k_gather<32><<<2048, 256, 0, stream>>>(rowptr, ecsr, dinv, xw2, agg2, sum2, sq2);
    k_stats_fin<32><<<1, 32, 0, stream>>>(sum2, sq2, g2, be2, scale2, shift2);

    // ---- BN+ELU fused with pooling, then MLP head ----
    k_bn_elu_pool<<<NN * 32 / 256, 256, 0, stream>>>(agg2, scale2, shift2, batch,
                                                     meanacc, maxacc, counts);
    k_mlp<<<NG, 64, 0, stream>>>(meanacc, maxacc, counts, Wm1, bm1, Wm2, bm2, out);
}

// Round 4
// 584.294 us; speedup vs baseline: 1.9885x; 1.3933x over previous
//
#include <hip/hip_runtime.h>
#include <math.h>

constexpr int NN = 100000;
constexpr int NE = 1600000;
constexpr int NG = 512;
constexpr int NBLK = (NN + 255) / 256;   // 391 scan blocks

__device__ __forceinline__ float eluf(float x) {
    return x > 0.f ? x : expm1f(x);
}

__global__ void k_deg(const int* __restrict__ dst, int* __restrict__ deg) {
    int e = blockIdx.x * blockDim.x + threadIdx.x;
    if (e < NE) atomicAdd(&deg[dst[e]], 1);
}

__global__ void k_dinv(const int* __restrict__ deg, float* __restrict__ dinv) {
    int n = blockIdx.x * blockDim.x + threadIdx.x;
    if (n < NN) dinv[n] = rsqrtf((float)deg[n] + 1.0f);
}

// --- 3-kernel exclusive scan of deg -> rowptr (and cursor copy) ---
__global__ void k_scan_block(const int* __restrict__ deg, int* __restrict__ tmp,
                             int* __restrict__ part) {
    __shared__ int sh[256];
    int tid = threadIdx.x;
    int i = blockIdx.x * 256 + tid;
    int v = (i < NN) ? deg[i] : 0;
    sh[tid] = v;
    __syncthreads();
    for (int off = 1; off < 256; off <<= 1) {
        int t = (tid >= off) ? sh[tid - off] : 0;
        __syncthreads();
        sh[tid] += t;
        __syncthreads();
    }
    if (i < NN) tmp[i] = sh[tid] - v;          // exclusive within block
    if (tid == 255) part[blockIdx.x] = sh[255];
}

__global__ void k_scan_part(int* __restrict__ part) {   // one block of 512
    __shared__ int sh[512];
    int tid = threadIdx.x;
    int v = (tid < NBLK) ? part[tid] : 0;
    sh[tid] = v;
    __syncthreads();
    for (int off = 1; off < 512; off <<= 1) {
        int t = (tid >= off) ? sh[tid - off] : 0;
        __syncthreads();
        sh[tid] += t;
        __syncthreads();
    }
    if (tid < NBLK) part[tid] = sh[tid] - v;   // exclusive block offsets
}

__global__ void k_scan_fin(const int* __restrict__ tmp, const int* __restrict__ part,
                           int* __restrict__ rowptr, int* __restrict__ cursor) {
    int i = blockIdx.x * 256 + threadIdx.x;
    if (i < NN) {
        int r = tmp[i] + part[i >> 8];
        rowptr[i] = r;
        cursor[i] = r;
    }
    if (i == 0) rowptr[NN] = NE;
}

// graph segment boundaries from the SORTED batch array: gptr[g] = lower_bound(batch, g)
__global__ void k_gptr(const int* __restrict__ batch, int* __restrict__ gptr) {
    int g = blockIdx.x * blockDim.x + threadIdx.x;
    if (g > NG) return;
    if (g == NG) { gptr[NG] = NN; return; }
    int lo = 0, hi = NN;
    while (lo < hi) {
        int mid = (lo + hi) >> 1;
        if (batch[mid] < g) lo = mid + 1; else hi = mid;
    }
    gptr[g] = lo;
}

// place edges into CSR buckets; ecsr = {src, coef} packed (one 8B store)
__global__ void k_place(const int* __restrict__ src, const int* __restrict__ dst,
                        const float* __restrict__ dinv, int* __restrict__ cursor,
                        int2* __restrict__ ecsr) {
    int e = blockIdx.x * blockDim.x + threadIdx.x;
    if (e >= NE) return;
    int s = src[e], d = dst[e];
    int pos = atomicAdd(&cursor[d], 1);
    ecsr[pos] = make_int2(s, __float_as_int(dinv[s] * dinv[d]));
}

// out[n][c] = dot(X[n][:K], W[:,c]); C consecutive threads share one row n
template<int K, int C>
__global__ void k_gemm_rows(const float* __restrict__ X, const float* __restrict__ W,
                            float* __restrict__ out) {
    int t = blockIdx.x * blockDim.x + threadIdx.x;
    if (t >= NN * C) return;
    int c = t & (C - 1);
    int n = t / C;
    const float* xr = X + n * K;
    float acc = 0.f;
#pragma unroll
    for (int k = 0; k < K; ++k) acc = fmaf(xr[k], W[k * C + c], acc);
    out[t] = acc;
}

// CSR gather, unrolled x8 for memory-level parallelism.
// C lanes per node (lanes = columns). Self-loop + BN-stats fused.
template<int C>
__global__ void k_gather(const int* __restrict__ rowptr, const int2* __restrict__ ecsr,
                         const float* __restrict__ dinv,
                         const float* __restrict__ xw, float* __restrict__ agg,
                         float* __restrict__ sums, float* __restrict__ sqs) {
    constexpr int NPB = 256 / C;
    int c = threadIdx.x & (C - 1);
    int local = threadIdx.x / C;
    float s_acc = 0.f, sq_acc = 0.f;
    for (int n = blockIdx.x * NPB + local; n < NN; n += gridDim.x * NPB) {
        int beg = rowptr[n], end = rowptr[n + 1];
        float acc = 0.f;
        int j = beg;
        for (; j + 8 <= end; j += 8) {
            int2 e0 = ecsr[j+0]; int2 e1 = ecsr[j+1];
            int2 e2 = ecsr[j+2]; int2 e3 = ecsr[j+3];
            int2 e4 = ecsr[j+4]; int2 e5 = ecsr[j+5];
            int2 e6 = ecsr[j+6]; int2 e7 = ecsr[j+7];
            float v0 = xw[e0.x * C + c]; float v1 = xw[e1.x * C + c];
            float v2 = xw[e2.x * C + c]; float v3 = xw[e3.x * C + c];
            float v4 = xw[e4.x * C + c]; float v5 = xw[e5.x * C + c];
            float v6 = xw[e6.x * C + c]; float v7 = xw[e7.x * C + c];
            acc = fmaf(v0, __int_as_float(e0.y), acc);
            acc = fmaf(v1, __int_as_float(e1.y), acc);
            acc = fmaf(v2, __int_as_float(e2.y), acc);
            acc = fmaf(v3, __int_as_float(e3.y), acc);
            acc = fmaf(v4, __int_as_float(e4.y), acc);
            acc = fmaf(v5, __int_as_float(e5.y), acc);
            acc = fmaf(v6, __int_as_float(e6.y), acc);
            acc = fmaf(v7, __int_as_float(e7.y), acc);
        }
        for (; j < end; ++j) {
            int2 e = ecsr[j];
            acc = fmaf(xw[e.x * C + c], __int_as_float(e.y), acc);
        }
        float di = dinv[n];
        acc = fmaf(xw[n * C + c], di * di, acc);   // self loop
        agg[n * C + c] = acc;
        s_acc += acc;
        sq_acc += acc * acc;
    }
    __shared__ float red[256];
    red[threadIdx.x] = s_acc;
    __syncthreads();
    if (threadIdx.x < C) {
        float tot = 0.f;
#pragma unroll
        for (int i = 0; i < NPB; ++i) tot += red[threadIdx.x + i * C];
        unsafeAtomicAdd(&sums[threadIdx.x], tot);
    }
    __syncthreads();
    red[threadIdx.x] = sq_acc;
    __syncthreads();
    if (threadIdx.x < C) {
        float tot = 0.f;
#pragma unroll
        for (int i = 0; i < NPB; ++i) tot += red[threadIdx.x + i * C];
        unsafeAtomicAdd(&sqs[threadIdx.x], tot);
    }
}

template<int C>
__global__ void k_stats_fin(const float* __restrict__ sums, const float* __restrict__ sqs,
                            const float* __restrict__ gamma, const float* __restrict__ beta,
                            float* __restrict__ scale, float* __restrict__ shift) {
    int c = threadIdx.x;
    if (c < C) {
        float mu = sums[c] * (1.0f / NN);
        float var = sqs[c] * (1.0f / NN) - mu * mu;
        float sc = gamma[c] * rsqrtf(var + 1e-5f);
        scale[c] = sc;
        shift[c] = beta[c] - mu * sc;
    }
}

// fused: h1 = elu(bn(agg1)) staged in LDS, then xw2 = h1 @ W2  (h1 never hits HBM)
__global__ void k_bn_gemm2(const float* __restrict__ agg1, const float* __restrict__ scale,
                           const float* __restrict__ shift, const float* __restrict__ W2,
                           float* __restrict__ xw2) {
    __shared__ float sh[8 * 64];
    __shared__ float sW[64 * 32];
    int tid = threadIdx.x;
#pragma unroll
    for (int i = tid; i < 64 * 32; i += 256) sW[i] = W2[i];
    int base = blockIdx.x * 8;
#pragma unroll
    for (int i = tid; i < 512; i += 256) {
        int r = i >> 6, cc = i & 63;
        int n = base + r;
        sh[i] = (n < NN) ? eluf(fmaf(agg1[n * 64 + cc], scale[cc], shift[cc])) : 0.f;
    }
    __syncthreads();
    int r = tid >> 5, c = tid & 31;   // 8 rows x 32 cols
    int n = base + r;
    if (n < NN) {
        float acc = 0.f;
#pragma unroll
        for (int k = 0; k < 64; ++k) acc = fmaf(sh[r * 64 + k], sW[k * 32 + c], acc);
        xw2[n * 32 + c] = acc;
    }
}

// segment pooling: one block per graph (batch is sorted -> contiguous segment).
// BN+ELU fused on the read; register+LDS reduce; NO atomics.
__global__ void k_pool_seg(const float* __restrict__ agg2, const float* __restrict__ scale,
                           const float* __restrict__ shift, const int* __restrict__ gptr,
                           float* __restrict__ gpool) {
    int g = blockIdx.x;
    int c = threadIdx.x & 31, r = threadIdx.x >> 5;   // 8 rows x 32 cols
    int beg = gptr[g], end = gptr[g + 1];
    float s = 0.f, m = -INFINITY;
    for (int n = beg + r; n < end; n += 8) {
        float v = eluf(fmaf(agg2[n * 32 + c], scale[c], shift[c]));
        s += v;
        m = fmaxf(m, v);
    }
    __shared__ float red[256];
    red[threadIdx.x] = s;
    __syncthreads();
    float stot = 0.f, mtot = -INFINITY;
    if (r == 0) {
#pragma unroll
        for (int i = 0; i < 8; ++i) stot += red[i * 32 + c];
    }
    __syncthreads();
    red[threadIdx.x] = m;
    __syncthreads();
    if (r == 0) {
#pragma unroll
        for (int i = 0; i < 8; ++i) mtot = fmaxf(mtot, red[i * 32 + c]);
        int cnt = end - beg;
        gpool[g * 64 + c] = stot / fmaxf((float)cnt, 1.f);
        gpool[g * 64 + 32 + c] = (cnt > 0) ? mtot : 0.f;
    }
}

__global__ void k_mlp(const float* __restrict__ gpool,
                      const float* __restrict__ Wm1, const float* __restrict__ bm1,
                      const float* __restrict__ Wm2, const float* __restrict__ bm2,
                      float* __restrict__ out) {
    int g = blockIdx.x;
    int t = threadIdx.x; // 64
    __shared__ float gr[64];
    __shared__ float h[32];
    gr[t] = gpool[g * 64 + t];
    __syncthreads();
    if (t < 32) {
        float acc = bm1[t];
#pragma unroll
        for (int k = 0; k < 64; ++k) acc = fmaf(gr[k], Wm1[k * 32 + t], acc);
        h[t] = eluf(acc);
    }
    __syncthreads();
    if (t < 2) {
        float acc = bm2[t];
#pragma unroll
        for (int k = 0; k < 32; ++k) acc = fmaf(h[k], Wm2[k * 2 + t], acc);
        out[g * 2 + t] = acc;
    }
}

extern "C" void kernel_launch(void* const* d_in, const int* in_sizes, int n_in,
                              void* d_out, int out_size, void* d_ws, size_t ws_size,
                              hipStream_t stream) {
    const float* x    = (const float*)d_in[0];
    const int*   eidx = (const int*)d_in[1];
    const int*   src  = eidx;
    const int*   dst  = eidx + NE;
    const int*   batch = (const int*)d_in[3];
    const float* W1  = (const float*)d_in[4];
    const float* g1  = (const float*)d_in[6];
    const float* be1 = (const float*)d_in[7];
    const float* W2  = (const float*)d_in[8];
    const float* g2  = (const float*)d_in[10];
    const float* be2 = (const float*)d_in[11];
    const float* Wm1 = (const float*)d_in[12];
    const float* bm1 = (const float*)d_in[13];
    const float* Wm2 = (const float*)d_in[14];
    const float* bm2 = (const float*)d_in[15];
    float* out = (float*)d_out;

    // ---- workspace layout ----
    int*   deg_i  = (int*)d_ws;                  // 100000
    int*   rowptr = deg_i + 100000;              // 100032 (incl +1 slot)
    int*   cursor = rowptr + 100032;             // 100000
    int*   tmp    = cursor + 100000;             // 100000
    int*   part   = tmp + 100000;                // 512
    int*   gptr   = part + 512;                  // 513 (+pad to 544)
    int2*  ecsr   = (int2*)(gptr + 544);         // 1600000 int2 (8B aligned)
    float* dinv   = (float*)(ecsr + 1600000);    // 100000
    float* S      = dinv + 100000;               // stats + gpool
    float* A      = S + 33664;                   // 6400000: xw1 -> [xw2|agg2]
    float* B      = A + 6400000;                 // 6400000: agg1

    float* sum1 = S;          float* sq1 = S + 64;
    float* scale1 = S + 128;  float* shift1 = S + 192;
    float* sum2 = S + 256;    float* sq2 = S + 288;
    float* scale2 = S + 320;  float* shift2 = S + 352;
    float* gpool  = S + 384;               // 512*64

    float* xw1  = A;
    float* agg1 = B;
    float* xw2  = A;                  // xw1 dead once agg1 + stats done
    float* agg2 = A + 3200000;

    // ---- init (just the 384 stat floats; pooling needs no init now) ----
    hipMemsetAsync(deg_i, 0, NN * sizeof(int), stream);
    hipMemsetAsync(S, 0, 384 * sizeof(float), stream);

    // ---- degree / dinv / CSR build / graph segments ----
    k_deg<<<NE / 256, 256, 0, stream>>>(dst, deg_i);
    k_dinv<<<NBLK, 256, 0, stream>>>(deg_i, dinv);
    k_scan_block<<<NBLK, 256, 0, stream>>>(deg_i, tmp, part);
    k_scan_part<<<1, 512, 0, stream>>>(part);
    k_scan_fin<<<NBLK, 256, 0, stream>>>(tmp, part, rowptr, cursor);
    k_place<<<NE / 256, 256, 0, stream>>>(src, dst, dinv, cursor, ecsr);
    k_gptr<<<3, 256, 0, stream>>>(batch, gptr);

    // ---- layer 1 (bias dropped: BN is shift-invariant) ----
    k_gemm_rows<66, 64><<<NN * 64 / 256, 256, 0, stream>>>(x, W1, xw1);
    k_gather<64><<<2048, 256, 0, stream>>>(rowptr, ecsr, dinv, xw1, agg1, sum1, sq1);
    k_stats_fin<64><<<1, 64, 0, stream>>>(sum1, sq1, g1, be1, scale1, shift1);

    // ---- layer 2 (BN+ELU of layer 1 fused into the GEMM) ----
    k_bn_gemm2<<<(NN + 7) / 8, 256, 0, stream>>>(agg1, scale1, shift1, W2, xw2);
    k_gather<32><<<2048, 256, 0, stream>>>(rowptr, ecsr, dinv, xw2, agg2, sum2, sq2);
    k_stats_fin<32><<<1, 32, 0, stream>>>(sum2, sq2, g2, be2, scale2, shift2);

    // ---- segment pooling (BN+ELU fused, no atomics), then MLP head ----
    k_pool_seg<<<NG, 256, 0, stream>>>(agg2, scale2, shift2, gptr, gpool);
    k_mlp<<<NG, 64, 0, stream>>>(gpool, Wm1, bm1, Wm2, bm2, out);
}

// Round 5
// 525.890 us; speedup vs baseline: 2.2094x; 1.1111x over previous
//
#include <hip/hip_runtime.h>
#include <math.h>

constexpr int NN = 100000;
constexpr int NE = 1600000;
constexpr int NG = 512;
constexpr int NBLK = (NN + 255) / 256;   // 391 scan blocks

typedef unsigned short bf16_t;
__device__ __forceinline__ bf16_t f2bf(float f) {
    unsigned u = __float_as_uint(f);
    unsigned r = (u + 0x7fffu + ((u >> 16) & 1u)) >> 16;   // round-nearest-even
    return (bf16_t)r;
}
__device__ __forceinline__ float bf2f(bf16_t h) {
    return __uint_as_float(((unsigned)h) << 16);
}

__device__ __forceinline__ float eluf(float x) {
    return x > 0.f ? x : expm1f(x);
}

__global__ void k_deg(const int* __restrict__ dst, int* __restrict__ deg) {
    int e = blockIdx.x * blockDim.x + threadIdx.x;
    if (e < NE) atomicAdd(&deg[dst[e]], 1);
}

__global__ void k_dinv(const int* __restrict__ deg, float* __restrict__ dinv) {
    int n = blockIdx.x * blockDim.x + threadIdx.x;
    if (n < NN) dinv[n] = rsqrtf((float)deg[n] + 1.0f);
}

// --- 3-kernel exclusive scan of deg -> rowptr (and cursor copy) ---
__global__ void k_scan_block(const int* __restrict__ deg, int* __restrict__ tmp,
                             int* __restrict__ part) {
    __shared__ int sh[256];
    int tid = threadIdx.x;
    int i = blockIdx.x * 256 + tid;
    int v = (i < NN) ? deg[i] : 0;
    sh[tid] = v;
    __syncthreads();
    for (int off = 1; off < 256; off <<= 1) {
        int t = (tid >= off) ? sh[tid - off] : 0;
        __syncthreads();
        sh[tid] += t;
        __syncthreads();
    }
    if (i < NN) tmp[i] = sh[tid] - v;          // exclusive within block
    if (tid == 255) part[blockIdx.x] = sh[255];
}

__global__ void k_scan_part(int* __restrict__ part) {   // one block of 512
    __shared__ int sh[512];
    int tid = threadIdx.x;
    int v = (tid < NBLK) ? part[tid] : 0;
    sh[tid] = v;
    __syncthreads();
    for (int off = 1; off < 512; off <<= 1) {
        int t = (tid >= off) ? sh[tid - off] : 0;
        __syncthreads();
        sh[tid] += t;
        __syncthreads();
    }
    if (tid < NBLK) part[tid] = sh[tid] - v;   // exclusive block offsets
}

__global__ void k_scan_fin(const int* __restrict__ tmp, const int* __restrict__ part,
                           int* __restrict__ rowptr, int* __restrict__ cursor) {
    int i = blockIdx.x * 256 + threadIdx.x;
    if (i < NN) {
        int r = tmp[i] + part[i >> 8];
        rowptr[i] = r;
        cursor[i] = r;
    }
    if (i == 0) rowptr[NN] = NE;
}

// graph segment boundaries from the SORTED batch array: gptr[g] = lower_bound(batch, g)
__global__ void k_gptr(const int* __restrict__ batch, int* __restrict__ gptr) {
    int g = blockIdx.x * blockDim.x + threadIdx.x;
    if (g > NG) return;
    if (g == NG) { gptr[NG] = NN; return; }
    int lo = 0, hi = NN;
    while (lo < hi) {
        int mid = (lo + hi) >> 1;
        if (batch[mid] < g) lo = mid + 1; else hi = mid;
    }
    gptr[g] = lo;
}

// place edges into CSR buckets; ecsr = {src, coef} packed (one 8B store)
__global__ void k_place(const int* __restrict__ src, const int* __restrict__ dst,
                        const float* __restrict__ dinv, int* __restrict__ cursor,
                        int2* __restrict__ ecsr) {
    int e = blockIdx.x * blockDim.x + threadIdx.x;
    if (e >= NE) return;
    int s = src[e], d = dst[e];
    int pos = atomicAdd(&cursor[d], 1);
    ecsr[pos] = make_int2(s, __float_as_int(dinv[s] * dinv[d]));
}

// LDS-tiled layer-1 GEMM: 64 nodes x 64 cols per block, bf16 output.
// x-tile + full W1 staged in LDS; x reads are LDS broadcasts, W reads stride-1.
__global__ void k_gemm1(const float* __restrict__ x, const float* __restrict__ W1,
                        bf16_t* __restrict__ xw1) {
    __shared__ float sx[64 * 66];   // 16.9 KB
    __shared__ float sw[66 * 64];   // 16.9 KB
    int tid = threadIdx.x;
    for (int i = tid; i < 66 * 64; i += 256) sw[i] = W1[i];
    int base = blockIdx.x * 64;
    int rows = min(64, NN - base);
    int cnt = rows * 66;
    for (int i = tid; i < cnt; i += 256) sx[i] = x[base * 66 + i];
    __syncthreads();
    int c = tid & 63, rg = tid >> 6;     // 4 row-groups x 64 cols
    float acc[16];
#pragma unroll
    for (int i = 0; i < 16; ++i) acc[i] = 0.f;
    for (int k = 0; k < 66; ++k) {
        float wv = sw[k * 64 + c];
#pragma unroll
        for (int rr = 0; rr < 16; ++rr)
            acc[rr] = fmaf(sx[(rg * 16 + rr) * 66 + k], wv, acc[rr]);
    }
#pragma unroll
    for (int rr = 0; rr < 16; ++rr) {
        int n = base + rg * 16 + rr;
        if (n < NN) xw1[n * 64 + c] = f2bf(acc[rr]);
    }
}

// CSR gather, unrolled x8 for memory-level parallelism; bf16 xw/agg, fp32 math.
// C lanes per node (lanes = columns). Self-loop + BN-stats fused.
template<int C>
__global__ void k_gather(const int* __restrict__ rowptr, const int2* __restrict__ ecsr,
                         const float* __restrict__ dinv,
                         const bf16_t* __restrict__ xw, bf16_t* __restrict__ agg,
                         float* __restrict__ sums, float* __restrict__ sqs) {
    constexpr int NPB = 256 / C;
    int c = threadIdx.x & (C - 1);
    int local = threadIdx.x / C;
    float s_acc = 0.f, sq_acc = 0.f;
    for (int n = blockIdx.x * NPB + local; n < NN; n += gridDim.x * NPB) {
        int beg = rowptr[n], end = rowptr[n + 1];
        float acc = 0.f;
        int j = beg;
        for (; j + 8 <= end; j += 8) {
            int2 e0 = ecsr[j+0]; int2 e1 = ecsr[j+1];
            int2 e2 = ecsr[j+2]; int2 e3 = ecsr[j+3];
            int2 e4 = ecsr[j+4]; int2 e5 = ecsr[j+5];
            int2 e6 = ecsr[j+6]; int2 e7 = ecsr[j+7];
            float v0 = bf2f(xw[e0.x * C + c]); float v1 = bf2f(xw[e1.x * C + c]);
            float v2 = bf2f(xw[e2.x * C + c]); float v3 = bf2f(xw[e3.x * C + c]);
            float v4 = bf2f(xw[e4.x * C + c]); float v5 = bf2f(xw[e5.x * C + c]);
            float v6 = bf2f(xw[e6.x * C + c]); float v7 = bf2f(xw[e7.x * C + c]);
            acc = fmaf(v0, __int_as_float(e0.y), acc);
            acc = fmaf(v1, __int_as_float(e1.y), acc);
            acc = fmaf(v2, __int_as_float(e2.y), acc);
            acc = fmaf(v3, __int_as_float(e3.y), acc);
            acc = fmaf(v4, __int_as_float(e4.y), acc);
            acc = fmaf(v5, __int_as_float(e5.y), acc);
            acc = fmaf(v6, __int_as_float(e6.y), acc);
            acc = fmaf(v7, __int_as_float(e7.y), acc);
        }
        for (; j < end; ++j) {
            int2 e = ecsr[j];
            acc = fmaf(bf2f(xw[e.x * C + c]), __int_as_float(e.y), acc);
        }
        float di = dinv[n];
        acc = fmaf(bf2f(xw[n * C + c]), di * di, acc);   // self loop
        agg[n * C + c] = f2bf(acc);
        s_acc += acc;
        sq_acc += acc * acc;
    }
    __shared__ float red[256];
    red[threadIdx.x] = s_acc;
    __syncthreads();
    if (threadIdx.x < C) {
        float tot = 0.f;
#pragma unroll
        for (int i = 0; i < NPB; ++i) tot += red[threadIdx.x + i * C];
        unsafeAtomicAdd(&sums[threadIdx.x], tot);
    }
    __syncthreads();
    red[threadIdx.x] = sq_acc;
    __syncthreads();
    if (threadIdx.x < C) {
        float tot = 0.f;
#pragma unroll
        for (int i = 0; i < NPB; ++i) tot += red[threadIdx.x + i * C];
        unsafeAtomicAdd(&sqs[threadIdx.x], tot);
    }
}

template<int C>
__global__ void k_stats_fin(const float* __restrict__ sums, const float* __restrict__ sqs,
                            const float* __restrict__ gamma, const float* __restrict__ beta,
                            float* __restrict__ scale, float* __restrict__ shift) {
    int c = threadIdx.x;
    if (c < C) {
        float mu = sums[c] * (1.0f / NN);
        float var = sqs[c] * (1.0f / NN) - mu * mu;
        float sc = gamma[c] * rsqrtf(var + 1e-5f);
        scale[c] = sc;
        shift[c] = beta[c] - mu * sc;
    }
}

// fused: h1 = elu(bn(agg1)) staged in LDS, then xw2 = h1 @ W2 (h1 never hits HBM)
__global__ void k_bn_gemm2(const bf16_t* __restrict__ agg1, const float* __restrict__ scale,
                           const float* __restrict__ shift, const float* __restrict__ W2,
                           bf16_t* __restrict__ xw2) {
    __shared__ float sh[8 * 64];
    __shared__ float sW[64 * 32];
    int tid = threadIdx.x;
#pragma unroll
    for (int i = tid; i < 64 * 32; i += 256) sW[i] = W2[i];
    int base = blockIdx.x * 8;
#pragma unroll
    for (int i = tid; i < 512; i += 256) {
        int r = i >> 6, cc = i & 63;
        int n = base + r;
        sh[i] = (n < NN) ? eluf(fmaf(bf2f(agg1[n * 64 + cc]), scale[cc], shift[cc])) : 0.f;
    }
    __syncthreads();
    int r = tid >> 5, c = tid & 31;   // 8 rows x 32 cols
    int n = base + r;
    if (n < NN) {
        float acc = 0.f;
#pragma unroll
        for (int k = 0; k < 64; ++k) acc = fmaf(sh[r * 64 + k], sW[k * 32 + c], acc);
        xw2[n * 32 + c] = f2bf(acc);
    }
}

// segment pooling: one block per graph (batch is sorted -> contiguous segment).
// BN+ELU fused on the read; register+LDS reduce; NO atomics.
__global__ void k_pool_seg(const bf16_t* __restrict__ agg2, const float* __restrict__ scale,
                           const float* __restrict__ shift, const int* __restrict__ gptr,
                           float* __restrict__ gpool) {
    int g = blockIdx.x;
    int c = threadIdx.x & 31, r = threadIdx.x >> 5;   // 8 rows x 32 cols
    int beg = gptr[g], end = gptr[g + 1];
    float s = 0.f, m = -INFINITY;
    for (int n = beg + r; n < end; n += 8) {
        float v = eluf(fmaf(bf2f(agg2[n * 32 + c]), scale[c], shift[c]));
        s += v;
        m = fmaxf(m, v);
    }
    __shared__ float red[256];
    red[threadIdx.x] = s;
    __syncthreads();
    float stot = 0.f, mtot = -INFINITY;
    if (r == 0) {
#pragma unroll
        for (int i = 0; i < 8; ++i) stot += red[i * 32 + c];
    }
    __syncthreads();
    red[threadIdx.x] = m;
    __syncthreads();
    if (r == 0) {
#pragma unroll
        for (int i = 0; i < 8; ++i) mtot = fmaxf(mtot, red[i * 32 + c]);
        int cnt = end - beg;
        gpool[g * 64 + c] = stot / fmaxf((float)cnt, 1.f);
        gpool[g * 64 + 32 + c] = (cnt > 0) ? mtot : 0.f;
    }
}

__global__ void k_mlp(const float* __restrict__ gpool,
                      const float* __restrict__ Wm1, const float* __restrict__ bm1,
                      const float* __restrict__ Wm2, const float* __restrict__ bm2,
                      float* __restrict__ out) {
    int g = blockIdx.x;
    int t = threadIdx.x; // 64
    __shared__ float gr[64];
    __shared__ float h[32];
    gr[t] = gpool[g * 64 + t];
    __syncthreads();
    if (t < 32) {
        float acc = bm1[t];
#pragma unroll
        for (int k = 0; k < 64; ++k) acc = fmaf(gr[k], Wm1[k * 32 + t], acc);
        h[t] = eluf(acc);
    }
    __syncthreads();
    if (t < 2) {
        float acc = bm2[t];
#pragma unroll
        for (int k = 0; k < 32; ++k) acc = fmaf(h[k], Wm2[k * 2 + t], acc);
        out[g * 2 + t] = acc;
    }
}

extern "C" void kernel_launch(void* const* d_in, const int* in_sizes, int n_in,
                              void* d_out, int out_size, void* d_ws, size_t ws_size,
                              hipStream_t stream) {
    const float* x    = (const float*)d_in[0];
    const int*   eidx = (const int*)d_in[1];
    const int*   src  = eidx;
    const int*   dst  = eidx + NE;
    const int*   batch = (const int*)d_in[3];
    const float* W1  = (const float*)d_in[4];
    const float* g1  = (const float*)d_in[6];
    const float* be1 = (const float*)d_in[7];
    const float* W2  = (const float*)d_in[8];
    const float* g2  = (const float*)d_in[10];
    const float* be2 = (const float*)d_in[11];
    const float* Wm1 = (const float*)d_in[12];
    const float* bm1 = (const float*)d_in[13];
    const float* Wm2 = (const float*)d_in[14];
    const float* bm2 = (const float*)d_in[15];
    float* out = (float*)d_out;

    // ---- workspace layout ----
    int*    deg_i  = (int*)d_ws;                  // 100000
    int*    rowptr = deg_i + 100000;              // 100032 (incl +1 slot)
    int*    cursor = rowptr + 100032;             // 100000
    int*    tmp    = cursor + 100000;             // 100000
    int*    part   = tmp + 100000;                // 512
    int*    gptr   = part + 512;                  // 544 (513 used; keeps 8B align)
    int2*   ecsr   = (int2*)(gptr + 544);         // 1600000 int2
    float*  dinv   = (float*)(ecsr + 1600000);    // 100000
    float*  S      = dinv + 100000;               // stats + gpool (384 + 32768)
    bf16_t* xw1    = (bf16_t*)(S + 33664);        // NN*64 bf16
    bf16_t* agg1   = xw1 + 6400000;               // NN*64 bf16
    bf16_t* xw2    = agg1 + 6400000;              // NN*32 bf16
    bf16_t* agg2   = xw2 + 3200000;               // NN*32 bf16

    float* sum1 = S;          float* sq1 = S + 64;
    float* scale1 = S + 128;  float* shift1 = S + 192;
    float* sum2 = S + 256;    float* sq2 = S + 288;
    float* scale2 = S + 320;  float* shift2 = S + 352;
    float* gpool  = S + 384;               // 512*64

    // ---- init (just the 384 stat floats; pooling needs no init now) ----
    hipMemsetAsync(deg_i, 0, NN * sizeof(int), stream);
    hipMemsetAsync(S, 0, 384 * sizeof(float), stream);

    // ---- degree / dinv / CSR build / graph segments ----
    k_deg<<<NE / 256, 256, 0, stream>>>(dst, deg_i);
    k_dinv<<<NBLK, 256, 0, stream>>>(deg_i, dinv);
    k_scan_block<<<NBLK, 256, 0, stream>>>(deg_i, tmp, part);
    k_scan_part<<<1, 512, 0, stream>>>(part);
    k_scan_fin<<<NBLK, 256, 0, stream>>>(tmp, part, rowptr, cursor);
    k_place<<<NE / 256, 256, 0, stream>>>(src, dst, dinv, cursor, ecsr);
    k_gptr<<<3, 256, 0, stream>>>(batch, gptr);

    // ---- layer 1 (bias dropped: BN is shift-invariant) ----
    k_gemm1<<<(NN + 63) / 64, 256, 0, stream>>>(x, W1, xw1);
    k_gather<64><<<2048, 256, 0, stream>>>(rowptr, ecsr, dinv, xw1, agg1, sum1, sq1);
    k_stats_fin<64><<<1, 64, 0, stream>>>(sum1, sq1, g1, be1, scale1, shift1);

    // ---- layer 2 (BN+ELU of layer 1 fused into the GEMM) ----
    k_bn_gemm2<<<(NN + 7) / 8, 256, 0, stream>>>(agg1, scale1, shift1, W2, xw2);
    k_gather<32><<<2048, 256, 0, stream>>>(rowptr, ecsr, dinv, xw2, agg2, sum2, sq2);
    k_stats_fin<32><<<1, 32, 0, stream>>>(sum2, sq2, g2, be2, scale2, shift2);

    // ---- segment pooling (BN+ELU fused, no atomics), then MLP head ----
    k_pool_seg<<<NG, 256, 0, stream>>>(agg2, scale2, shift2, gptr, gpool);
    k_mlp<<<NG, 64, 0, stream>>>(gpool, Wm1, bm1, Wm2, bm2, out);
}

// Round 6
// 488.946 us; speedup vs baseline: 2.3763x; 1.0756x over previous
//
#include <hip/hip_runtime.h>
#include <math.h>

constexpr int NN = 100000;
constexpr int NE = 1600000;
constexpr int NG = 512;
constexpr int NBLK = (NN + 255) / 256;   // 391 scan blocks

typedef unsigned short bf16_t;
__device__ __forceinline__ bf16_t f2bf(float f) {
    unsigned u = __float_as_uint(f);
    unsigned r = (u + 0x7fffu + ((u >> 16) & 1u)) >> 16;   // round-nearest-even
    return (bf16_t)r;
}
__device__ __forceinline__ float bf2f(bf16_t h) {
    return __uint_as_float(((unsigned)h) << 16);
}

__device__ __forceinline__ float eluf(float x) {
    return x > 0.f ? x : expm1f(x);
}

__global__ void k_deg(const int* __restrict__ dst, int* __restrict__ deg) {
    int e = blockIdx.x * blockDim.x + threadIdx.x;
    if (e < NE) atomicAdd(&deg[dst[e]], 1);
}

// --- 3-kernel exclusive scan of deg -> rowptr (dinv fused here) ---
__global__ void k_scan_block(const int* __restrict__ deg, float* __restrict__ dinv,
                             int* __restrict__ tmp, int* __restrict__ part) {
    __shared__ int sh[256];
    int tid = threadIdx.x;
    int i = blockIdx.x * 256 + tid;
    int v = (i < NN) ? deg[i] : 0;
    if (i < NN) dinv[i] = rsqrtf((float)v + 1.0f);
    sh[tid] = v;
    __syncthreads();
    for (int off = 1; off < 256; off <<= 1) {
        int t = (tid >= off) ? sh[tid - off] : 0;
        __syncthreads();
        sh[tid] += t;
        __syncthreads();
    }
    if (i < NN) tmp[i] = sh[tid] - v;          // exclusive within block
    if (tid == 255) part[blockIdx.x] = sh[255];
}

__global__ void k_scan_part(int* __restrict__ part) {   // one block of 512
    __shared__ int sh[512];
    int tid = threadIdx.x;
    int v = (tid < NBLK) ? part[tid] : 0;
    sh[tid] = v;
    __syncthreads();
    for (int off = 1; off < 512; off <<= 1) {
        int t = (tid >= off) ? sh[tid - off] : 0;
        __syncthreads();
        sh[tid] += t;
        __syncthreads();
    }
    if (tid < NBLK) part[tid] = sh[tid] - v;   // exclusive block offsets
}

__global__ void k_scan_fin(const int* __restrict__ tmp, const int* __restrict__ part,
                           int* __restrict__ rowptr, int* __restrict__ cursor) {
    int i = blockIdx.x * 256 + threadIdx.x;
    if (i < NN) {
        int r = tmp[i] + part[i >> 8];
        rowptr[i] = r;
        cursor[i] = r;
    }
    if (i == 0) rowptr[NN] = NE;
}

// graph segment boundaries from the SORTED batch array: gptr[g] = lower_bound(batch, g)
__global__ void k_gptr(const int* __restrict__ batch, int* __restrict__ gptr) {
    int g = blockIdx.x * blockDim.x + threadIdx.x;
    if (g > NG) return;
    if (g == NG) { gptr[NG] = NN; return; }
    int lo = 0, hi = NN;
    while (lo < hi) {
        int mid = (lo + hi) >> 1;
        if (batch[mid] < g) lo = mid + 1; else hi = mid;
    }
    gptr[g] = lo;
}

// place edges into CSR buckets; ecsr = {src, coef} packed (one 8B store)
__global__ void k_place(const int* __restrict__ src, const int* __restrict__ dst,
                        const float* __restrict__ dinv, int* __restrict__ cursor,
                        int2* __restrict__ ecsr) {
    int e = blockIdx.x * blockDim.x + threadIdx.x;
    if (e >= NE) return;
    int s = src[e], d = dst[e];
    int pos = atomicAdd(&cursor[d], 1);
    ecsr[pos] = make_int2(s, __float_as_int(dinv[s] * dinv[d]));
}

// LDS-tiled layer-1 GEMM: 64 nodes x 64 cols per block, bf16 output.
__global__ void k_gemm1(const float* __restrict__ x, const float* __restrict__ W1,
                        bf16_t* __restrict__ xw1) {
    __shared__ float sx[64 * 66];   // 16.9 KB
    __shared__ float sw[66 * 64];   // 16.9 KB
    int tid = threadIdx.x;
    for (int i = tid; i < 66 * 64; i += 256) sw[i] = W1[i];
    int base = blockIdx.x * 64;
    int rows = min(64, NN - base);
    int cnt = rows * 66;
    for (int i = tid; i < cnt; i += 256) sx[i] = x[base * 66 + i];
    __syncthreads();
    int c = tid & 63, rg = tid >> 6;     // 4 row-groups x 64 cols
    float acc[16];
#pragma unroll
    for (int i = 0; i < 16; ++i) acc[i] = 0.f;
    for (int k = 0; k < 66; ++k) {
        float wv = sw[k * 64 + c];
#pragma unroll
        for (int rr = 0; rr < 16; ++rr)
            acc[rr] = fmaf(sx[(rg * 16 + rr) * 66 + k], wv, acc[rr]);
    }
#pragma unroll
    for (int rr = 0; rr < 16; ++rr) {
        int n = base + rg * 16 + rr;
        if (n < NN) xw1[n * 64 + c] = f2bf(acc[rr]);
    }
}

// CSR gather: 2 nodes per lane-group, masked 8-wide rounds (no serial tail).
// 16 random row-loads in flight per group. bf16 payload, fp32 math.
template<int C>
__global__ void k_gather(const int* __restrict__ rowptr, const int2* __restrict__ ecsr,
                         const float* __restrict__ dinv,
                         const bf16_t* __restrict__ xw, bf16_t* __restrict__ agg,
                         float* __restrict__ sums, float* __restrict__ sqs) {
    constexpr int NPB = 256 / C;
    int c = threadIdx.x & (C - 1);
    int local = threadIdx.x / C;
    float s_acc = 0.f, sq_acc = 0.f;
    for (int n0 = (blockIdx.x * NPB + local) * 2; n0 < NN;
         n0 += gridDim.x * NPB * 2) {
        int n1 = n0 + 1;
        bool has1 = n1 < NN;
        int beg0 = rowptr[n0], end0 = rowptr[n0 + 1];
        int beg1 = beg0, end1 = beg0;
        if (has1) { beg1 = rowptr[n1]; end1 = rowptr[n1 + 1]; }
        int safe0 = (beg0 < NE) ? beg0 : 0;
        int safe1 = (beg1 < NE) ? beg1 : 0;
        float acc0 = 0.f, acc1 = 0.f;
        int j0 = beg0, j1 = beg1;
        while (j0 < end0 || j1 < end1) {
            int2 e0[8], e1[8];
#pragma unroll
            for (int k = 0; k < 8; ++k) {
                int idx = j0 + k;
                e0[k] = ecsr[(idx < end0) ? idx : safe0];
                if (idx >= end0) e0[k].y = 0;            // coef = 0 -> no-op
            }
#pragma unroll
            for (int k = 0; k < 8; ++k) {
                int idx = j1 + k;
                e1[k] = ecsr[(idx < end1) ? idx : safe1];
                if (idx >= end1) e1[k].y = 0;
            }
            float v0[8], v1[8];
#pragma unroll
            for (int k = 0; k < 8; ++k) v0[k] = bf2f(xw[e0[k].x * C + c]);
#pragma unroll
            for (int k = 0; k < 8; ++k) v1[k] = bf2f(xw[e1[k].x * C + c]);
#pragma unroll
            for (int k = 0; k < 8; ++k) acc0 = fmaf(v0[k], __int_as_float(e0[k].y), acc0);
#pragma unroll
            for (int k = 0; k < 8; ++k) acc1 = fmaf(v1[k], __int_as_float(e1[k].y), acc1);
            j0 += 8; j1 += 8;
        }
        float di0 = dinv[n0];
        acc0 = fmaf(bf2f(xw[n0 * C + c]), di0 * di0, acc0);   // self loop
        agg[n0 * C + c] = f2bf(acc0);
        s_acc += acc0;
        sq_acc += acc0 * acc0;
        if (has1) {
            float di1 = dinv[n1];
            acc1 = fmaf(bf2f(xw[n1 * C + c]), di1 * di1, acc1);
            agg[n1 * C + c] = f2bf(acc1);
            s_acc += acc1;
            sq_acc += acc1 * acc1;
        }
    }
    __shared__ float red[256];
    red[threadIdx.x] = s_acc;
    __syncthreads();
    if (threadIdx.x < C) {
        float tot = 0.f;
#pragma unroll
        for (int i = 0; i < NPB; ++i) tot += red[threadIdx.x + i * C];
        unsafeAtomicAdd(&sums[threadIdx.x], tot);
    }
    __syncthreads();
    red[threadIdx.x] = sq_acc;
    __syncthreads();
    if (threadIdx.x < C) {
        float tot = 0.f;
#pragma unroll
        for (int i = 0; i < NPB; ++i) tot += red[threadIdx.x + i * C];
        unsafeAtomicAdd(&sqs[threadIdx.x], tot);
    }
}

// fused: derive scale/shift from sums/sqs in-block, h1 = elu(bn(agg1)) in LDS,
// xw2 = h1 @ W2 (h1 never hits HBM)
__global__ void k_bn_gemm2(const bf16_t* __restrict__ agg1, const float* __restrict__ sums,
                           const float* __restrict__ sqs, const float* __restrict__ gamma,
                           const float* __restrict__ beta, const float* __restrict__ W2,
                           bf16_t* __restrict__ xw2) {
    __shared__ float sh[8 * 64];
    __shared__ float sW[64 * 32];
    __shared__ float sscale[64], sshift[64];
    int tid = threadIdx.x;
    if (tid < 64) {
        float mu = sums[tid] * (1.0f / NN);
        float var = sqs[tid] * (1.0f / NN) - mu * mu;
        float sc = gamma[tid] * rsqrtf(var + 1e-5f);
        sscale[tid] = sc;
        sshift[tid] = beta[tid] - mu * sc;
    }
#pragma unroll
    for (int i = tid; i < 64 * 32; i += 256) sW[i] = W2[i];
    __syncthreads();
    int base = blockIdx.x * 8;
#pragma unroll
    for (int i = tid; i < 512; i += 256) {
        int r = i >> 6, cc = i & 63;
        int n = base + r;
        sh[i] = (n < NN) ? eluf(fmaf(bf2f(agg1[n * 64 + cc]), sscale[cc], sshift[cc])) : 0.f;
    }
    __syncthreads();
    int r = tid >> 5, c = tid & 31;   // 8 rows x 32 cols
    int n = base + r;
    if (n < NN) {
        float acc = 0.f;
#pragma unroll
        for (int k = 0; k < 64; ++k) acc = fmaf(sh[r * 64 + k], sW[k * 32 + c], acc);
        xw2[n * 32 + c] = f2bf(acc);
    }
}

// segment pooling: one block per graph; scale/shift derived in-block; no atomics.
__global__ void k_pool_seg(const bf16_t* __restrict__ agg2, const float* __restrict__ sums,
                           const float* __restrict__ sqs, const float* __restrict__ gamma,
                           const float* __restrict__ beta, const int* __restrict__ gptr,
                           float* __restrict__ gpool) {
    __shared__ float sscale[32], sshift[32];
    int tid = threadIdx.x;
    if (tid < 32) {
        float mu = sums[tid] * (1.0f / NN);
        float var = sqs[tid] * (1.0f / NN) - mu * mu;
        float sc = gamma[tid] * rsqrtf(var + 1e-5f);
        sscale[tid] = sc;
        sshift[tid] = beta[tid] - mu * sc;
    }
    __syncthreads();
    int g = blockIdx.x;
    int c = tid & 31, r = tid >> 5;   // 8 rows x 32 cols
    int beg = gptr[g], end = gptr[g + 1];
    float scl = sscale[c], shf = sshift[c];
    float s = 0.f, m = -INFINITY;
    for (int n = beg + r; n < end; n += 8) {
        float v = eluf(fmaf(bf2f(agg2[n * 32 + c]), scl, shf));
        s += v;
        m = fmaxf(m, v);
    }
    __shared__ float red[256];
    red[tid] = s;
    __syncthreads();
    float stot = 0.f, mtot = -INFINITY;
    if (r == 0) {
#pragma unroll
        for (int i = 0; i < 8; ++i) stot += red[i * 32 + c];
    }
    __syncthreads();
    red[tid] = m;
    __syncthreads();
    if (r == 0) {
#pragma unroll
        for (int i = 0; i < 8; ++i) mtot = fmaxf(mtot, red[i * 32 + c]);
        int cnt = end - beg;
        gpool[g * 64 + c] = stot / fmaxf((float)cnt, 1.f);
        gpool[g * 64 + 32 + c] = (cnt > 0) ? mtot : 0.f;
    }
}

__global__ void k_mlp(const float* __restrict__ gpool,
                      const float* __restrict__ Wm1, const float* __restrict__ bm1,
                      const float* __restrict__ Wm2, const float* __restrict__ bm2,
                      float* __restrict__ out) {
    int g = blockIdx.x;
    int t = threadIdx.x; // 64
    __shared__ float gr[64];
    __shared__ float h[32];
    gr[t] = gpool[g * 64 + t];
    __syncthreads();
    if (t < 32) {
        float acc = bm1[t];
#pragma unroll
        for (int k = 0; k < 64; ++k) acc = fmaf(gr[k], Wm1[k * 32 + t], acc);
        h[t] = eluf(acc);
    }
    __syncthreads();
    if (t < 2) {
        float acc = bm2[t];
#pragma unroll
        for (int k = 0; k < 32; ++k) acc = fmaf(h[k], Wm2[k * 2 + t], acc);
        out[g * 2 + t] = acc;
    }
}

extern "C" void kernel_launch(void* const* d_in, const int* in_sizes, int n_in,
                              void* d_out, int out_size, void* d_ws, size_t ws_size,
                              hipStream_t stream) {
    const float* x    = (const float*)d_in[0];
    const int*   eidx = (const int*)d_in[1];
    const int*   src  = eidx;
    const int*   dst  = eidx + NE;
    const int*   batch = (const int*)d_in[3];
    const float* W1  = (const float*)d_in[4];
    const float* g1  = (const float*)d_in[6];
    const float* be1 = (const float*)d_in[7];
    const float* W2  = (const float*)d_in[8];
    const float* g2  = (const float*)d_in[10];
    const float* be2 = (const float*)d_in[11];
    const float* Wm1 = (const float*)d_in[12];
    const float* bm1 = (const float*)d_in[13];
    const float* Wm2 = (const float*)d_in[14];
    const float* bm2 = (const float*)d_in[15];
    float* out = (float*)d_out;

    // ---- workspace layout ----
    int*    deg_i  = (int*)d_ws;                  // 100000
    int*    rowptr = deg_i + 100000;              // 100032 (incl +1 slot)
    int*    cursor = rowptr + 100032;             // 100000
    int*    tmp    = cursor + 100000;              // 100000
    int*    part   = tmp + 100000;                // 512
    int*    gptr   = part + 512;                  // 544 (513 used; keeps 8B align)
    int2*   ecsr   = (int2*)(gptr + 544);         // 1600000 int2
    float*  dinv   = (float*)(ecsr + 1600000);    // 100000
    float*  S      = dinv + 100000;               // stats + gpool (384 + 32768)
    bf16_t* xw1    = (bf16_t*)(S + 33664);        // NN*64 bf16
    bf16_t* agg1   = xw1 + 6400000;               // NN*64 bf16
    bf16_t* xw2    = agg1 + 6400000;              // NN*32 bf16
    bf16_t* agg2   = xw2 + 3200000;               // NN*32 bf16

    float* sum1 = S;          float* sq1 = S + 64;
    float* sum2 = S + 256;    float* sq2 = S + 288;
    float* gpool  = S + 384;               // 512*64

    // ---- init ----
    hipMemsetAsync(deg_i, 0, NN * sizeof(int), stream);
    hipMemsetAsync(S, 0, 384 * sizeof(float), stream);

    // ---- degree / dinv / CSR build / graph segments ----
    k_deg<<<NE / 256, 256, 0, stream>>>(dst, deg_i);
    k_scan_block<<<NBLK, 256, 0, stream>>>(deg_i, dinv, tmp, part);
    k_scan_part<<<1, 512, 0, stream>>>(part);
    k_scan_fin<<<NBLK, 256, 0, stream>>>(tmp, part, rowptr, cursor);
    k_place<<<NE / 256, 256, 0, stream>>>(src, dst, dinv, cursor, ecsr);
    k_gptr<<<3, 256, 0, stream>>>(batch, gptr);

    // ---- layer 1 (bias dropped: BN is shift-invariant) ----
    k_gemm1<<<(NN + 63) / 64, 256, 0, stream>>>(x, W1, xw1);
    k_gather<64><<<2048, 256, 0, stream>>>(rowptr, ecsr, dinv, xw1, agg1, sum1, sq1);

    // ---- layer 2 (BN+ELU of layer 1 + stats-finalize fused into the GEMM) ----
    k_bn_gemm2<<<(NN + 7) / 8, 256, 0, stream>>>(agg1, sum1, sq1, g1, be1, W2, xw2);
    k_gather<32><<<2048, 256, 0, stream>>>(rowptr, ecsr, dinv, xw2, agg2, sum2, sq2);

    // ---- segment pooling (BN+ELU + stats fused, no atomics), then MLP head ----
    k_pool_seg<<<NG, 256, 0, stream>>>(agg2, sum2, sq2, g2, be2, gptr, gpool);
    k_mlp<<<NG, 64, 0, stream>>>(gpool, Wm1, bm1, Wm2, bm2, out);
}